// Round 5
// baseline (1729.905 us; speedup 1.0000x reference)
//
#include <hip/hip_runtime.h>
#include <cstdint>

#define NOUTC 131072
#define NINC  16384

using uint = unsigned int;

__device__ __forceinline__ uint fkey(float v){
  uint u = __float_as_uint(v);
  return (u & 0x80000000u) ? ~u : (u | 0x80000000u);
}

// ---------------------------------------------------------------------------
// c0: 64->64, 27 taps. Block = 64 rows, 4 waves (cout-split: wave g owns couts
// [16g,16g+16)). Double-buffered LDS staging of gathered rows (coalesced),
// compute reads LDS row-per-lane, weights via wave-uniform scalar loads.
// LDS row stride 65 floats -> all b32 accesses <=2-way bank aliased (free).
// ---------------------------------------------------------------------------
__global__ __launch_bounds__(256)
void conv_c0_v3(const float* __restrict__ feats, const int* __restrict__ nbr,
                const float* __restrict__ Wc0, const float* __restrict__ bias,
                float* __restrict__ outp)
{
  __shared__ float sbuf[2 * 64 * 65];
  const int t    = threadIdx.x;
  const int gu   = __builtin_amdgcn_readfirstlane(t >> 6);
  const int lane = t & 63;
  const int base = blockIdx.x * 64;
  const int sr   = t >> 2;   // staging row 0..63
  const int sq   = t & 3;    // 64B quarter of the row

  float acc[16];
  #pragma unroll
  for (int i = 0; i < 16; ++i) acc[i] = 0.f;

  // prologue: load tap 0 rows into regs
  float4 g0, g1, g2, g3;
  {
    int idx = nbr[base + sr];
    const float4* src = reinterpret_cast<const float4*>(feats + (size_t)idx * 64) + sq * 4;
    g0 = src[0]; g1 = src[1]; g2 = src[2]; g3 = src[3];
  }

  #pragma unroll 1
  for (int k = 0; k < 27; ++k) {
    float* buf = sbuf + (k & 1) * 4160;
    float* wp  = buf + sr * 65 + sq * 16;
    wp[0]=g0.x; wp[1]=g0.y; wp[2]=g0.z; wp[3]=g0.w;
    wp[4]=g1.x; wp[5]=g1.y; wp[6]=g1.z; wp[7]=g1.w;
    wp[8]=g2.x; wp[9]=g2.y; wp[10]=g2.z; wp[11]=g2.w;
    wp[12]=g3.x; wp[13]=g3.y; wp[14]=g3.z; wp[15]=g3.w;
    __syncthreads();
    if (k < 26) {
      int idx = nbr[(size_t)(k + 1) * NOUTC + base + sr];
      const float4* src = reinterpret_cast<const float4*>(feats + (size_t)idx * 64) + sq * 4;
      g0 = src[0]; g1 = src[1]; g2 = src[2]; g3 = src[3];
    }
    const float* frow = buf + lane * 65;
    const float* w = Wc0 + k * 4096 + gu * 16;   // element [ci*64 + j], uniform
    #pragma unroll
    for (int ci = 0; ci < 64; ++ci) {
      float f = frow[ci];
      #pragma unroll
      for (int j = 0; j < 16; ++j)
        acc[j] = fmaf(f, w[ci * 64 + j], acc[j]);
    }
    __syncthreads();
  }

  const int n = base + lane;
  float* dst = outp + (size_t)n * 64 + gu * 16;
  #pragma unroll
  for (int q = 0; q < 4; ++q) {
    float4 o;
    float v0 = acc[4*q+0] + bias[gu*16 + 4*q+0]; o.x = v0 > 0.f ? v0 : 0.f;
    float v1 = acc[4*q+1] + bias[gu*16 + 4*q+1]; o.y = v1 > 0.f ? v1 : 0.f;
    float v2 = acc[4*q+2] + bias[gu*16 + 4*q+2]; o.z = v2 > 0.f ? v2 : 0.f;
    float v3 = acc[4*q+3] + bias[gu*16 + 4*q+3]; o.w = v3 > 0.f ? v3 : 0.f;
    reinterpret_cast<float4*>(dst)[q] = o;
  }
}

// ---------------------------------------------------------------------------
// A: t0 = relu(spconv(cur,W00)+b00) [64->16, 27 taps]
//    t1 = relu(cur@W10+b10) (fused at identity tap k=13)
// cin-split: wave g owns ci in [16g,16g+16), computes ALL 16 couts of both.
// LDS tree reduction of partials at the end; wave 0 writes.
// ---------------------------------------------------------------------------
__global__ __launch_bounds__(256)
void conv_A_v3(const float* __restrict__ feats, const int* __restrict__ nbr,
               const float* __restrict__ W00i, const float* __restrict__ b00i,
               const float* __restrict__ W10i, const float* __restrict__ b10i,
               float* __restrict__ t0, float* __restrict__ t1)
{
  __shared__ float sbuf[2 * 64 * 65];
  const int t    = threadIdx.x;
  const int gu   = __builtin_amdgcn_readfirstlane(t >> 6);
  const int lane = t & 63;
  const int base = blockIdx.x * 64;
  const int sr   = t >> 2;
  const int sq   = t & 3;

  float acc0[16], acc1[16];
  #pragma unroll
  for (int i = 0; i < 16; ++i) { acc0[i] = 0.f; acc1[i] = 0.f; }

  float4 g0, g1, g2, g3;
  {
    int idx = nbr[base + sr];
    const float4* src = reinterpret_cast<const float4*>(feats + (size_t)idx * 64) + sq * 4;
    g0 = src[0]; g1 = src[1]; g2 = src[2]; g3 = src[3];
  }

  #pragma unroll 1
  for (int k = 0; k < 27; ++k) {
    float* buf = sbuf + (k & 1) * 4160;
    float* wp  = buf + sr * 65 + sq * 16;
    wp[0]=g0.x; wp[1]=g0.y; wp[2]=g0.z; wp[3]=g0.w;
    wp[4]=g1.x; wp[5]=g1.y; wp[6]=g1.z; wp[7]=g1.w;
    wp[8]=g2.x; wp[9]=g2.y; wp[10]=g2.z; wp[11]=g2.w;
    wp[12]=g3.x; wp[13]=g3.y; wp[14]=g3.z; wp[15]=g3.w;
    __syncthreads();
    if (k < 26) {
      int idx = nbr[(size_t)(k + 1) * NOUTC + base + sr];
      const float4* src = reinterpret_cast<const float4*>(feats + (size_t)idx * 64) + sq * 4;
      g0 = src[0]; g1 = src[1]; g2 = src[2]; g3 = src[3];
    }
    const float* frow = buf + lane * 65 + gu * 16;
    const float* w = W00i + k * 1024 + gu * 256;   // [e*16 + j]
    #pragma unroll
    for (int e = 0; e < 16; ++e) {
      float f = frow[e];
      #pragma unroll
      for (int j = 0; j < 16; ++j)
        acc0[j] = fmaf(f, w[e * 16 + j], acc0[j]);
    }
    if (k == 13) {
      const float* w1 = W10i + gu * 256;
      #pragma unroll
      for (int e = 0; e < 16; ++e) {
        float f = frow[e];
        #pragma unroll
        for (int j = 0; j < 16; ++j)
          acc1[j] = fmaf(f, w1[e * 16 + j], acc1[j]);
      }
    }
    __syncthreads();
  }

  // tree reduction across the 4 cin-split waves (LDS reuse, stride 33)
  __syncthreads();
  float* red = sbuf;           // 2 slots x 64 x 33
  if (gu >= 2) {
    float* d = red + (size_t)(gu - 2) * 2112 + lane * 33;
    #pragma unroll
    for (int j = 0; j < 16; ++j) { d[j] = acc0[j]; d[16 + j] = acc1[j]; }
  }
  __syncthreads();
  if (gu < 2) {
    const float* s = red + (size_t)gu * 2112 + lane * 33;
    #pragma unroll
    for (int j = 0; j < 16; ++j) { acc0[j] += s[j]; acc1[j] += s[16 + j]; }
  }
  __syncthreads();
  if (gu == 1) {
    float* d = red + lane * 33;
    #pragma unroll
    for (int j = 0; j < 16; ++j) { d[j] = acc0[j]; d[16 + j] = acc1[j]; }
  }
  __syncthreads();
  if (gu == 0) {
    const float* s = red + lane * 33;
    const int n = base + lane;
    float* d0 = t0 + (size_t)n * 16;
    float* d1 = t1 + (size_t)n * 16;
    #pragma unroll
    for (int q = 0; q < 4; ++q) {
      float4 o0, o1; float v;
      v = acc0[4*q+0] + s[4*q+0] + b00i[4*q+0]; o0.x = v > 0.f ? v : 0.f;
      v = acc0[4*q+1] + s[4*q+1] + b00i[4*q+1]; o0.y = v > 0.f ? v : 0.f;
      v = acc0[4*q+2] + s[4*q+2] + b00i[4*q+2]; o0.z = v > 0.f ? v : 0.f;
      v = acc0[4*q+3] + s[4*q+3] + b00i[4*q+3]; o0.w = v > 0.f ? v : 0.f;
      v = acc1[4*q+0] + s[16+4*q+0] + b10i[4*q+0]; o1.x = v > 0.f ? v : 0.f;
      v = acc1[4*q+1] + s[16+4*q+1] + b10i[4*q+1]; o1.y = v > 0.f ? v : 0.f;
      v = acc1[4*q+2] + s[16+4*q+2] + b10i[4*q+2]; o1.z = v > 0.f ? v : 0.f;
      v = acc1[4*q+3] + s[16+4*q+3] + b10i[4*q+3]; o1.w = v > 0.f ? v : 0.f;
      reinterpret_cast<float4*>(d0)[q] = o0;
      reinterpret_cast<float4*>(d1)[q] = o1;
    }
  }
}

// ---------------------------------------------------------------------------
// B: o0 = spconv(t0,W01)+b01 [16->32]; t2 = relu(spconv(t1,W11)+b11) [16->16];
//    o1 = t2@W12+b12; nxt = concat(o0,o1)+cur.
// Staged row = t0[16] || t1[16] (stride 33). Wave w=(a,b): ci in [8a,8a+8),
// o0 couts [16b,16b+16), t2 couts [8b,8b+8). Pair-reduce a=1 -> a=0, t2
// broadcast via LDS, all 4 waves compute an o1 slice [8w,8w+8).
// ---------------------------------------------------------------------------
__global__ __launch_bounds__(256)
void conv_B_v3(const float* __restrict__ t0, const float* __restrict__ t1,
               const float* __restrict__ cur, const int* __restrict__ nbr,
               const float* __restrict__ W01i, const float* __restrict__ b01i,
               const float* __restrict__ W11i, const float* __restrict__ b11i,
               const float* __restrict__ W12i, const float* __restrict__ b12i,
               float* __restrict__ nxt)
{
  __shared__ float sbuf[4224];   // staging 2*64*33 ; tail: red 2*64*25 + t2s 16*64
  const int t    = threadIdx.x;
  const int w    = __builtin_amdgcn_readfirstlane(t >> 6);
  const int a    = w >> 1, b = w & 1;
  const int lane = t & 63;
  const int base = blockIdx.x * 64;
  const int sr   = t >> 2;
  const int sq   = t & 3;

  float acc01[16], acc11[8];
  #pragma unroll
  for (int i = 0; i < 16; ++i) acc01[i] = 0.f;
  #pragma unroll
  for (int i = 0; i < 8; ++i) acc11[i] = 0.f;

  float4 g0, g1;
  {
    int idx = nbr[base + sr];
    g0 = reinterpret_cast<const float4*>(t0 + (size_t)idx * 16)[sq];
    g1 = reinterpret_cast<const float4*>(t1 + (size_t)idx * 16)[sq];
  }

  #pragma unroll 1
  for (int k = 0; k < 27; ++k) {
    float* buf = sbuf + (k & 1) * 2112;
    float* wp  = buf + sr * 33 + sq * 4;
    wp[0]=g0.x; wp[1]=g0.y; wp[2]=g0.z; wp[3]=g0.w;
    wp[16]=g1.x; wp[17]=g1.y; wp[18]=g1.z; wp[19]=g1.w;
    __syncthreads();
    if (k < 26) {
      int idx = nbr[(size_t)(k + 1) * NOUTC + base + sr];
      g0 = reinterpret_cast<const float4*>(t0 + (size_t)idx * 16)[sq];
      g1 = reinterpret_cast<const float4*>(t1 + (size_t)idx * 16)[sq];
    }
    const float* f0 = buf + lane * 33 + 8 * a;
    const float* f1 = f0 + 16;
    const float* w01 = W01i + k * 512 + (8 * a) * 32 + 16 * b;  // [e*32 + j]
    const float* w11 = W11i + k * 256 + (8 * a) * 16 + 8 * b;   // [e*16 + j]
    #pragma unroll
    for (int e = 0; e < 8; ++e) {
      float fa = f0[e];
      #pragma unroll
      for (int j = 0; j < 16; ++j)
        acc01[j] = fmaf(fa, w01[e * 32 + j], acc01[j]);
      float fb = f1[e];
      #pragma unroll
      for (int j = 0; j < 8; ++j)
        acc11[j] = fmaf(fb, w11[e * 16 + j], acc11[j]);
    }
    __syncthreads();
  }

  __syncthreads();
  float* red = sbuf;              // [2][64][25]
  float* t2s = sbuf + 3200;       // [16][64]
  if (a == 1) {
    float* d = red + (size_t)b * 1600 + lane * 25;
    #pragma unroll
    for (int j = 0; j < 16; ++j) d[j] = acc01[j];
    #pragma unroll
    for (int j = 0; j < 8; ++j) d[16 + j] = acc11[j];
  }
  __syncthreads();
  if (a == 0) {
    const float* s = red + (size_t)b * 1600 + lane * 25;
    #pragma unroll
    for (int j = 0; j < 16; ++j) acc01[j] += s[j];
    #pragma unroll
    for (int j = 0; j < 8; ++j) {
      float v = acc11[j] + s[16 + j] + b11i[8 * b + j];
      t2s[(8 * b + j) * 64 + lane] = v > 0.f ? v : 0.f;
    }
  }
  __syncthreads();

  const int n = base + lane;
  // o1 slice [8w, 8w+8)
  float t2[16];
  #pragma unroll
  for (int u = 0; u < 16; ++u) t2[u] = t2s[u * 64 + lane];
  float o1[8];
  #pragma unroll
  for (int j = 0; j < 8; ++j) o1[j] = b12i[8 * w + j];
  #pragma unroll
  for (int u = 0; u < 16; ++u)
    #pragma unroll
    for (int j = 0; j < 8; ++j)
      o1[j] = fmaf(t2[u], W12i[u * 32 + 8 * w + j], o1[j]);
  {
    const float* rs = cur + (size_t)n * 64 + 32 + 8 * w;
    float* dst = nxt + (size_t)n * 64 + 32 + 8 * w;
    float4 r0 = *reinterpret_cast<const float4*>(rs);
    float4 r1 = *reinterpret_cast<const float4*>(rs + 4);
    float4 s0 = {o1[0]+r0.x, o1[1]+r0.y, o1[2]+r0.z, o1[3]+r0.w};
    float4 s1 = {o1[4]+r1.x, o1[5]+r1.y, o1[6]+r1.z, o1[7]+r1.w};
    *reinterpret_cast<float4*>(dst)     = s0;
    *reinterpret_cast<float4*>(dst + 4) = s1;
  }
  if (a == 0) {
    const float* rs = cur + (size_t)n * 64 + 16 * b;
    float* dst = nxt + (size_t)n * 64 + 16 * b;
    #pragma unroll
    for (int q = 0; q < 4; ++q) {
      float4 r = reinterpret_cast<const float4*>(rs)[q];
      float4 s;
      s.x = acc01[4*q+0] + b01i[16*b + 4*q+0] + r.x;
      s.y = acc01[4*q+1] + b01i[16*b + 4*q+1] + r.y;
      s.z = acc01[4*q+2] + b01i[16*b + 4*q+2] + r.z;
      s.w = acc01[4*q+3] + b01i[16*b + 4*q+3] + r.w;
      reinterpret_cast<float4*>(dst)[q] = s;
    }
  }
}

// ---------------------------------------------------------------------------
// upsample: fa[(n*8+k)*64+:] = relu(x[n]@Wup[k]+bup). k uniform per block,
// wave g computes couts [16g,16g+16). Original weight layout (scalar loads).
// ---------------------------------------------------------------------------
__global__ __launch_bounds__(256)
void up2_v3(const float* __restrict__ x, const float* __restrict__ Wup,
            const float* __restrict__ bup, float* __restrict__ outp)
{
  const int gu   = __builtin_amdgcn_readfirstlane(threadIdx.x >> 6);
  const int lane = threadIdx.x & 63;
  const int k    = blockIdx.x & 7;
  const int n    = (blockIdx.x >> 3) * 64 + lane;

  float acc[16];
  #pragma unroll
  for (int i = 0; i < 16; ++i) acc[i] = 0.f;

  const float4* src = reinterpret_cast<const float4*>(x + (size_t)n * 64);
  const float* w = Wup + k * 4096 + gu * 16;   // element [ci*64 + j]
  #pragma unroll
  for (int c = 0; c < 4; ++c) {
    float4 a0 = src[c*4+0], a1 = src[c*4+1], a2 = src[c*4+2], a3 = src[c*4+3];
    float fr[16];
    fr[0]=a0.x; fr[1]=a0.y; fr[2]=a0.z; fr[3]=a0.w;
    fr[4]=a1.x; fr[5]=a1.y; fr[6]=a1.z; fr[7]=a1.w;
    fr[8]=a2.x; fr[9]=a2.y; fr[10]=a2.z; fr[11]=a2.w;
    fr[12]=a3.x; fr[13]=a3.y; fr[14]=a3.z; fr[15]=a3.w;
    #pragma unroll
    for (int u = 0; u < 16; ++u)
      #pragma unroll
      for (int j = 0; j < 16; ++j)
        acc[j] = fmaf(fr[u], w[(c * 16 + u) * 64 + j], acc[j]);
  }

  float* dst = outp + ((size_t)n * 8 + k) * 64 + gu * 16;
  #pragma unroll
  for (int q = 0; q < 4; ++q) {
    float4 o;
    float v0 = acc[4*q+0] + bup[gu*16 + 4*q+0]; o.x = v0 > 0.f ? v0 : 0.f;
    float v1 = acc[4*q+1] + bup[gu*16 + 4*q+1]; o.y = v1 > 0.f ? v1 : 0.f;
    float v2 = acc[4*q+2] + bup[gu*16 + 4*q+2]; o.z = v2 > 0.f ? v2 : 0.f;
    float v3 = acc[4*q+3] + bup[gu*16 + 4*q+3]; o.w = v3 > 0.f ? v3 : 0.f;
    reinterpret_cast<float4*>(dst)[q] = o;
  }
}

// ---------------------------------------------------------------------------
// cls pass 1: g[n][k] = feats[n] . Wcls[k]
// ---------------------------------------------------------------------------
__global__ __launch_bounds__(256)
void cls1_kernel(const float* __restrict__ feats, const float* __restrict__ Wcls,
                 float* __restrict__ g)
{
  const int n = blockIdx.x * 256 + threadIdx.x;
  if (blockIdx.x == 0 && threadIdx.x < 28) g[(size_t)NOUTC * 28 + threadIdx.x] = 0.f;
  const float4* src = reinterpret_cast<const float4*>(feats + (size_t)n * 64);
  float f[64];
  #pragma unroll
  for (int j = 0; j < 16; ++j) {
    float4 a = src[j];
    f[4*j+0]=a.x; f[4*j+1]=a.y; f[4*j+2]=a.z; f[4*j+3]=a.w;
  }
  #pragma unroll 1
  for (int k = 0; k < 27; ++k) {
    const float* w = Wcls + k * 64;
    float s0 = 0.f, s1 = 0.f, s2 = 0.f, s3 = 0.f;
    #pragma unroll
    for (int j = 0; j < 16; ++j) {
      s0 = fmaf(f[j],      w[j],      s0);
      s1 = fmaf(f[16 + j], w[16 + j], s1);
      s2 = fmaf(f[32 + j], w[32 + j], s2);
      s3 = fmaf(f[48 + j], w[48 + j], s3);
    }
    g[(size_t)n * 28 + k] = (s0 + s1) + (s2 + s3);
  }
}

__global__ __launch_bounds__(256)
void cls2_kernel(const float* __restrict__ g, const int* __restrict__ nbr,
                 const float* __restrict__ bcls, float* __restrict__ out_cls)
{
  const int n = blockIdx.x * 256 + threadIdx.x;
  float s = bcls[0];
  #pragma unroll 1
  for (int k = 0; k < 27; ++k) {
    int idx = nbr[(size_t)k * NOUTC + n];
    s += g[(size_t)idx * 28 + k];
  }
  out_cls[n] = s;
}

// ---------------------------------------------------------------------------
// init / detect / top-k select / prune
// ---------------------------------------------------------------------------
__global__ void init_kernel(uint* hist1, uint* hist2, int* tie_cnt, int* flag,
                            float* fa, float* fb, float* t0, float* t1)
{
  int i = blockIdx.x * 256 + threadIdx.x;
  if (i < 65536) hist1[i] = 0;
  else if (i < 131072) hist2[i - 65536] = 0;
  if (i == 0) { tie_cnt[0] = 0; flag[0] = 0; }
  if (i < 64) { fa[(size_t)NOUTC * 64 + i] = 0.f; fb[(size_t)NOUTC * 64 + i] = 0.f; }
  if (i < 16) { t0[(size_t)NOUTC * 16 + i] = 0.f; t1[(size_t)NOUTC * 16 + i] = 0.f; }
}

__global__ void detect_kernel(const unsigned char* __restrict__ mt, int* flag)
{
  int i = blockIdx.x * 256 + threadIdx.x;
  int p = i * 4 + 1;
  if (p < NOUTC && mt[p] != 0) flag[0] = 1;
}

__global__ void hist1_kernel(const float* __restrict__ cls, uint* __restrict__ hist)
{
  for (int i = blockIdx.x * blockDim.x + threadIdx.x; i < NOUTC; i += gridDim.x * blockDim.x)
    atomicAdd(&hist[fkey(cls[i]) >> 16], 1u);
}

__global__ void scan1_kernel(const uint* __restrict__ hist, const int* __restrict__ nums,
                             uint* __restrict__ res)
{
  __shared__ uint chunk[256];
  const int t = threadIdx.x;
  uint s = 0;
  for (int j = 0; j < 256; ++j) s += hist[t * 256 + j];
  chunk[t] = s;
  __syncthreads();
  if (t == 0) {
    uint k = (uint)nums[0];
    uint cum = 0; int c = 255;
    for (; c > 0; --c) { if (cum + chunk[c] >= k) break; cum += chunk[c]; }
    int B = c * 256; uint cum2 = cum;
    for (int b = c * 256 + 255; b >= c * 256; --b) {
      if (cum2 + hist[b] >= k) { B = b; break; }
      cum2 += hist[b];
    }
    res[0] = (uint)B; res[1] = cum2;
  }
}

__global__ void hist2_kernel(const float* __restrict__ cls, const uint* __restrict__ res1,
                             uint* __restrict__ hist)
{
  const uint B = res1[0];
  for (int i = blockIdx.x * blockDim.x + threadIdx.x; i < NOUTC; i += gridDim.x * blockDim.x) {
    uint key = fkey(cls[i]);
    if ((key >> 16) == B) atomicAdd(&hist[key & 0xffffu], 1u);
  }
}

__global__ void scan2_kernel(const uint* __restrict__ hist, const uint* __restrict__ res1,
                             const int* __restrict__ nums, uint* __restrict__ res2)
{
  __shared__ uint chunk[256];
  const int t = threadIdx.x;
  uint s = 0;
  for (int j = 0; j < 256; ++j) s += hist[t * 256 + j];
  chunk[t] = s;
  __syncthreads();
  if (t == 0) {
    uint k = (uint)nums[0];
    uint cum = res1[1]; int c = 255;
    for (; c > 0; --c) { if (cum + chunk[c] >= k) break; cum += chunk[c]; }
    int L = c * 256; uint cum2 = cum;
    for (int b = c * 256 + 255; b >= c * 256; --b) {
      if (cum2 + hist[b] >= k) { L = b; break; }
      cum2 += hist[b];
    }
    res2[0] = (res1[0] << 16) | (uint)L;
    res2[1] = k - cum2;
  }
}

__global__ void mark_kernel(const float* __restrict__ cls, const uint* __restrict__ res2,
                            unsigned char* __restrict__ msel, int* tie_cnt, int* tie_idx)
{
  const uint T = res2[0];
  for (int i = blockIdx.x * blockDim.x + threadIdx.x; i < NOUTC; i += gridDim.x * blockDim.x) {
    uint key = fkey(cls[i]);
    msel[i] = key > T ? 1 : 0;
    if (key == T) {
      int p = atomicAdd(tie_cnt, 1);
      if (p < 4096) tie_idx[p] = i;
    }
  }
}

__global__ void tie_kernel(const uint* __restrict__ res2, const int* __restrict__ tie_cnt,
                           const int* __restrict__ tie_idx, unsigned char* __restrict__ msel)
{
  int need = (int)res2[1];
  int cnt = tie_cnt[0]; if (cnt > 4096) cnt = 4096;
  if (need <= 0) return;
  if (cnt <= need) {
    for (int i = threadIdx.x; i < cnt; i += 256) msel[tie_idx[i]] = 1;
  } else {
    for (int i = threadIdx.x; i < cnt; i += 256) {
      int my = tie_idx[i];
      int rank = 0;
      for (int j = 0; j < cnt; ++j) rank += (tie_idx[j] < my) ? 1 : 0;
      if (rank < need) msel[my] = 1;
    }
  }
}

__global__ void prune_kernel(const float* __restrict__ feats, const unsigned char* __restrict__ msel,
                             const void* __restrict__ mtrue, const int* __restrict__ flag,
                             float* __restrict__ dout)
{
  const unsigned char* mb = (const unsigned char*)mtrue;
  const int* mi = (const int*)mtrue;
  const bool bytes = (flag[0] != 0);
  float* pruned = dout + NOUTC;
  float* maskf  = dout + NOUTC + (size_t)NOUTC * 64;
  const float4* src = reinterpret_cast<const float4*>(feats);
  float4* dst = reinterpret_cast<float4*>(pruned);
  const int total = NOUTC * 16;
  for (int i = blockIdx.x * blockDim.x + threadIdx.x; i < total; i += gridDim.x * blockDim.x) {
    int n = i >> 4;
    bool mt = bytes ? (mb[n] != 0) : (mi[n] != 0);
    bool m = (msel[n] != 0) || mt;
    float4 v = src[i];
    float4 z = {0.f, 0.f, 0.f, 0.f};
    dst[i] = m ? v : z;
    if ((i & 15) == 0) maskf[n] = m ? 1.f : 0.f;
  }
}

// ---------------------------------------------------------------------------
extern "C" void kernel_launch(void* const* d_in, const int* in_sizes, int n_in,
                              void* d_out, int out_size, void* d_ws, size_t ws_size,
                              hipStream_t stream)
{
  const float* x    = (const float*)d_in[0];
  const float* Wup  = (const float*)d_in[1];
  const float* bup  = (const float*)d_in[2];
  const float* Wc0  = (const float*)d_in[3];
  const float* bc0  = (const float*)d_in[4];
  const float* W00  = (const float*)d_in[5];
  const float* b00  = (const float*)d_in[6];
  const float* W01  = (const float*)d_in[7];
  const float* b01  = (const float*)d_in[8];
  const float* W10  = (const float*)d_in[9];
  const float* b10  = (const float*)d_in[10];
  const float* W11  = (const float*)d_in[11];
  const float* b11  = (const float*)d_in[12];
  const float* W12  = (const float*)d_in[13];
  const float* b12  = (const float*)d_in[14];
  const float* Wcls = (const float*)d_in[15];
  const float* bcls = (const float*)d_in[16];
  const int*   nbr  = (const int*)d_in[17];
  const void*  mtrue= d_in[18];
  const int*   nums = (const int*)d_in[19];

  float* dout = (float*)d_out;

  float* fa = (float*)d_ws;                       // (N+1)*64
  float* t0 = fa + (size_t)(NOUTC + 1) * 64;      // (N+1)*16
  float* t1 = t0 + (size_t)(NOUTC + 1) * 16;      // (N+1)*16
  float* g  = t0;                                 // (N+1)*28 overlay (dead by cls time)
  uint*  hist1 = (uint*)(t1 + (size_t)(NOUTC + 1) * 16);
  uint*  hist2 = hist1 + 65536;
  uint*  res1  = hist2 + 65536;
  uint*  res2  = res1 + 2;
  int*   tie_cnt = (int*)(res2 + 2);
  int*   flag    = tie_cnt + 1;
  int*   tie_idx = flag + 1;
  unsigned char* msel = (unsigned char*)(tie_idx + 4096);
  float* fb = dout + NOUTC;   // (N+1)*64 parked in d_out's pruned+mask region

  init_kernel<<<512, 256, 0, stream>>>(hist1, hist2, tie_cnt, flag, fa, fb, t0, t1);
  detect_kernel<<<128, 256, 0, stream>>>((const unsigned char*)mtrue, flag);

  up2_v3<<<2048, 256, 0, stream>>>(x, Wup, bup, fa);
  conv_c0_v3<<<2048, 256, 0, stream>>>(fa, nbr, Wc0, bc0, fb);

  const float* cur = fb; float* nxt = fa;
  for (int i = 0; i < 3; ++i) {
    conv_A_v3<<<2048, 256, 0, stream>>>(cur, nbr,
        W00 + (size_t)i * 27 * 1024, b00 + i * 16,
        W10 + (size_t)i * 1024,      b10 + i * 16, t0, t1);
    conv_B_v3<<<2048, 256, 0, stream>>>(t0, t1, cur, nbr,
        W01 + (size_t)i * 27 * 512, b01 + i * 32,
        W11 + (size_t)i * 27 * 256, b11 + i * 16,
        W12 + (size_t)i * 512,      b12 + i * 32, nxt);
    float* tmp = (float*)cur; cur = nxt; nxt = tmp;
  }
  // final features in fa

  cls1_kernel<<<512, 256, 0, stream>>>(cur, Wcls, g);
  cls2_kernel<<<512, 256, 0, stream>>>(g, nbr, bcls, dout);

  hist1_kernel<<<512, 256, 0, stream>>>(dout, hist1);
  scan1_kernel<<<1, 256, 0, stream>>>(hist1, nums, res1);
  hist2_kernel<<<512, 256, 0, stream>>>(dout, res1, hist2);
  scan2_kernel<<<1, 256, 0, stream>>>(hist2, res1, nums, res2);
  mark_kernel<<<512, 256, 0, stream>>>(dout, res2, msel, tie_cnt, tie_idx);
  tie_kernel<<<1, 256, 0, stream>>>(res2, tie_cnt, tie_idx, msel);
  prune_kernel<<<4096, 256, 0, stream>>>(cur, msel, mtrue, flag, dout);
}